// Round 1
// baseline (1635.727 us; speedup 1.0000x reference)
//
#include <hip/hip_runtime.h>
#include <stdint.h>

typedef unsigned short u16;
typedef __bf16 bf16x8 __attribute__((ext_vector_type(8)));
typedef float f32x4 __attribute__((ext_vector_type(4)));

constexpr int T_ = 32768, D_ = 256, H_ = 8, L_ = 4, B_ = 64, NSENS_ = 5160;

__device__ __forceinline__ u16 f2b(float f) {
  uint32_t u = __builtin_bit_cast(uint32_t, f);
  u += 0x7fffu + ((u >> 16) & 1u);
  return (u16)(u >> 16);
}
__device__ __forceinline__ float b2f(u16 h) {
  uint32_t u = ((uint32_t)h) << 16;
  return __builtin_bit_cast(float, u);
}

__device__ __forceinline__ void gload16(const void* g, void* l) {
  __builtin_amdgcn_global_load_lds(
      (const __attribute__((address_space(1))) void*)g,
      (__attribute__((address_space(3))) void*)l, 16, 0, 0);
}

// ---------------- offsets via binary search (sorted dom_to_event_idx) --------
__global__ void k_offsets(const int* __restrict__ d2e, int* __restrict__ offs) {
  int t = threadIdx.x;
  if (t > B_) return;
  int lo = 0, hi = T_;
  while (lo < hi) { int mid = (lo + hi) >> 1; if (d2e[mid] < t) lo = mid + 1; else hi = mid; }
  offs[t] = lo;
}

// ---------------- f32 -> bf16 weight conversion ------------------------------
__global__ void k_f2b(const float* __restrict__ s, u16* __restrict__ d, int n) {
  int i = blockIdx.x * blockDim.x + threadIdx.x;
  int str = gridDim.x * blockDim.x;
  for (; i < n; i += str) d[i] = f2b(s[i]);
}

// ---------------- geo MLP per sensor -----------------------------------------
__global__ void k_geo(const float* __restrict__ geom, const float* __restrict__ w1,
                      const float* __restrict__ b1, const float* __restrict__ w2,
                      const float* __restrict__ b2, float* __restrict__ ge) {
  __shared__ float h1[128];
  int s = blockIdx.x, t = threadIdx.x;
  float g0 = geom[s * 3 + 0] * (1.0f / 500.0f);
  float g1 = geom[s * 3 + 1] * (1.0f / 500.0f);
  float g2 = geom[s * 3 + 2] * (1.0f / 500.0f);
  float a = g0 * w1[t * 3 + 0] + g1 * w1[t * 3 + 1] + g2 * w1[t * 3 + 2] + b1[t];
  h1[t] = 0.5f * a * (1.0f + erff(a * 0.70710678118654752f));
  __syncthreads();
  for (int c = t; c < 256; c += 128) {
    float acc = b2[c];
    const float* wr = w2 + c * 128;
#pragma unroll 8
    for (int k = 0; k < 128; ++k) acc += h1[k] * wr[k];
    ge[s * 256 + c] = acc;
  }
}

// ---------------- feat = dom_embeddings + ge[dom_ids] ------------------------
__global__ void k_feat(const float4* __restrict__ de, const float4* __restrict__ ge,
                       const int* __restrict__ dom_ids, float4* __restrict__ x) {
  int i = blockIdx.x * blockDim.x + threadIdx.x;
  if (i >= T_ * 64) return;
  int row = i >> 6, c = i & 63;
  int sid = dom_ids[row];
  float4 a = de[i];
  float4 b = ge[sid * 64 + c];
  float4 o;
  o.x = a.x + b.x; o.y = a.y + b.y; o.z = a.z + b.z; o.w = a.w + b.w;
  x[i] = o;
}

// ---------------- LayerNorm: f32 in -> bf16 out ------------------------------
__global__ void k_ln(const float* __restrict__ x, const float* __restrict__ w,
                     const float* __restrict__ b, u16* __restrict__ h) {
  int row = blockIdx.x * 4 + (threadIdx.x >> 6);
  int lane = threadIdx.x & 63;
  const float4 v = *(const float4*)(x + (size_t)row * 256 + lane * 4);
  float s = v.x + v.y + v.z + v.w;
  float q = v.x * v.x + v.y * v.y + v.z * v.z + v.w * v.w;
#pragma unroll
  for (int m = 1; m < 64; m <<= 1) { s += __shfl_xor(s, m); q += __shfl_xor(q, m); }
  float mean = s * (1.0f / 256.0f);
  float var = fmaxf(q * (1.0f / 256.0f) - mean * mean, 0.0f);
  float rs = 1.0f / sqrtf(var + 1e-5f);
  float4 wv = *(const float4*)(w + lane * 4);
  float4 bv = *(const float4*)(b + lane * 4);
  ushort4 o;
  o.x = f2b((v.x - mean) * rs * wv.x + bv.x);
  o.y = f2b((v.y - mean) * rs * wv.y + bv.y);
  o.z = f2b((v.z - mean) * rs * wv.z + bv.z);
  o.w = f2b((v.w - mean) * rs * wv.w + bv.w);
  *(ushort4*)(h + (size_t)row * 256 + lane * 4) = o;
}

// ---------------- bf16 MFMA GEMM: C = A(MxK) * W(NxK)^T + bias ---------------
// EPI: 0 = bf16 out, 1 = relu -> bf16 out, 2 = f32 residual accumulate (x += C)
template <int EPI>
__global__ __launch_bounds__(256) void k_gemm(const u16* __restrict__ A, const u16* __restrict__ W,
                                              const float* __restrict__ bias, void* __restrict__ out,
                                              int M, int N, int K) {
  __shared__ __align__(16) u16 As[128 * 32];
  __shared__ __align__(16) u16 Ws[128 * 32];
  const int tid = threadIdx.x, lane = tid & 63, wv = tid >> 6;
  const int wr = wv >> 1, wc = wv & 1;
  const int m0 = blockIdx.y * 128, n0 = blockIdx.x * 128;
  const int l16 = lane & 15, lhi = lane >> 4;
  f32x4 acc[4][4] = {};
  for (int kt = 0; kt < K; kt += 32) {
    __syncthreads();
#pragma unroll
    for (int c = 0; c < 2; ++c) {
      int bix = wv * 2048 + c * 1024 + lane * 16;
      int rowA = bix >> 6, off = bix & 63;
      const char* ga = (const char*)A + ((size_t)(m0 + rowA) * K + kt) * 2 + off;
      gload16(ga, (char*)As + wv * 2048 + c * 1024);
      const char* gw = (const char*)W + ((size_t)(n0 + rowA) * K + kt) * 2 + off;
      gload16(gw, (char*)Ws + wv * 2048 + c * 1024);
    }
    __syncthreads();
    bf16x8 af[4], bfr[4];
#pragma unroll
    for (int i = 0; i < 4; ++i) {
      af[i] = *(const bf16x8*)((const char*)As + (wr * 64 + i * 16 + l16) * 64 + lhi * 16);
      bfr[i] = *(const bf16x8*)((const char*)Ws + (wc * 64 + i * 16 + l16) * 64 + lhi * 16);
    }
#pragma unroll
    for (int i = 0; i < 4; ++i)
#pragma unroll
      for (int j = 0; j < 4; ++j)
        acc[i][j] = __builtin_amdgcn_mfma_f32_16x16x32_bf16(af[i], bfr[j], acc[i][j], 0, 0, 0);
  }
  float bv[4];
#pragma unroll
  for (int j = 0; j < 4; ++j) bv[j] = bias[n0 + wc * 64 + j * 16 + l16];
#pragma unroll
  for (int i = 0; i < 4; ++i)
#pragma unroll
    for (int j = 0; j < 4; ++j)
#pragma unroll
      for (int r = 0; r < 4; ++r) {
        int m = m0 + wr * 64 + i * 16 + lhi * 4 + r;
        int n = n0 + wc * 64 + j * 16 + l16;
        float val = acc[i][j][r] + bv[j];
        if (EPI == 0) {
          ((u16*)out)[(size_t)m * N + n] = f2b(val);
        } else if (EPI == 1) {
          ((u16*)out)[(size_t)m * N + n] = f2b(fmaxf(val, 0.0f));
        } else {
          ((float*)out)[(size_t)m * N + n] += val;
        }
      }
}

// ---------------- flash attention, one (qchunk, head, event) per block -------
__global__ __launch_bounds__(256) void k_attn(const u16* __restrict__ qkv, const int* __restrict__ offs,
                                              u16* __restrict__ ao) {
  const int e = blockIdx.z, hh = blockIdx.y, qc = blockIdx.x;
  const int off = offs[e], Se = offs[e + 1] - off;
  const int q0b = qc * 64;
  if (q0b >= Se) return;
  const int tid = threadIdx.x, lane = tid & 63, wv = tid >> 6;
  const int l16 = lane & 15, lhi = lane >> 4;
  __shared__ __align__(16) u16 Kl[32 * 32];
  __shared__ __align__(16) u16 Vt[32 * 32];
  __shared__ __align__(16) u16 Pl[4][512];

  const int q0 = q0b + wv * 16;
  int qrow = q0 + l16;
  int grow = off + min(qrow, Se - 1);
  bf16x8 qf = *(const bf16x8*)(qkv + (size_t)grow * 768 + hh * 32 + lhi * 8);

  f32x4 o0 = {}, o1 = {};
  float mrow[4], lrow[4];
#pragma unroll
  for (int r = 0; r < 4; ++r) { mrow[r] = -1e30f; lrow[r] = 0.0f; }
  const float scale = 0.17677669529663687f;

  for (int kb = 0; kb < Se; kb += 32) {
    __syncthreads();
    if (tid < 128) {
      int bix = tid * 16, rowk = bix >> 6, offb = bix & 63;
      int gk = off + min(kb + rowk, Se - 1);
      *(uint4*)((char*)Kl + bix) =
          *(const uint4*)((const char*)qkv + ((size_t)gk * 768 + 256 + hh * 32) * 2 + offb);
    } else if (tid < 160) {
      int kk = tid - 128;
      int gv = off + min(kb + kk, Se - 1);
      const u16* vr = qkv + (size_t)gv * 768 + 512 + hh * 32;
      u16 tmp[32];
      *(uint4*)(tmp + 0) = *(const uint4*)(vr + 0);
      *(uint4*)(tmp + 8) = *(const uint4*)(vr + 8);
      *(uint4*)(tmp + 16) = *(const uint4*)(vr + 16);
      *(uint4*)(tmp + 24) = *(const uint4*)(vr + 24);
#pragma unroll
      for (int d = 0; d < 32; ++d) Vt[d * 32 + kk] = tmp[d];
    }
    __syncthreads();

    f32x4 sc0 = {}, sc1 = {};
    bf16x8 k0 = *(const bf16x8*)((const char*)Kl + l16 * 64 + lhi * 16);
    bf16x8 k1 = *(const bf16x8*)((const char*)Kl + (16 + l16) * 64 + lhi * 16);
    sc0 = __builtin_amdgcn_mfma_f32_16x16x32_bf16(qf, k0, sc0, 0, 0, 0);
    sc1 = __builtin_amdgcn_mfma_f32_16x16x32_bf16(qf, k1, sc1, 0, 0, 0);

    float p0[4], p1[4], rmax[4];
#pragma unroll
    for (int r = 0; r < 4; ++r) {
      float s0 = sc0[r] * scale, s1 = sc1[r] * scale;
      if (kb + l16 >= Se) s0 = -1e30f;
      if (kb + 16 + l16 >= Se) s1 = -1e30f;
      p0[r] = s0; p1[r] = s1;
      rmax[r] = fmaxf(s0, s1);
    }
#pragma unroll
    for (int m = 1; m < 16; m <<= 1)
#pragma unroll
      for (int r = 0; r < 4; ++r) rmax[r] = fmaxf(rmax[r], __shfl_xor(rmax[r], m));
    float csc[4], rsum[4];
#pragma unroll
    for (int r = 0; r < 4; ++r) {
      float mn = fmaxf(mrow[r], rmax[r]);
      csc[r] = __expf(mrow[r] - mn);
      mrow[r] = mn;
      float e0 = __expf(p0[r] - mn), e1 = __expf(p1[r] - mn);
      p0[r] = e0; p1[r] = e1;
      rsum[r] = e0 + e1;
    }
#pragma unroll
    for (int m = 1; m < 16; m <<= 1)
#pragma unroll
      for (int r = 0; r < 4; ++r) rsum[r] += __shfl_xor(rsum[r], m);
#pragma unroll
    for (int r = 0; r < 4; ++r) {
      lrow[r] = lrow[r] * csc[r] + rsum[r];
      o0[r] *= csc[r];
      o1[r] *= csc[r];
    }
    u16* pw = Pl[wv];
#pragma unroll
    for (int r = 0; r < 4; ++r) {
      int prow = lhi * 4 + r;
      pw[prow * 32 + l16] = f2b(p0[r]);
      pw[prow * 32 + 16 + l16] = f2b(p1[r]);
    }
    bf16x8 pf = *(const bf16x8*)((const char*)Pl[wv] + l16 * 64 + lhi * 16);
    bf16x8 v0 = *(const bf16x8*)((const char*)Vt + l16 * 64 + lhi * 16);
    bf16x8 v1 = *(const bf16x8*)((const char*)Vt + (16 + l16) * 64 + lhi * 16);
    o0 = __builtin_amdgcn_mfma_f32_16x16x32_bf16(pf, v0, o0, 0, 0, 0);
    o1 = __builtin_amdgcn_mfma_f32_16x16x32_bf16(pf, v1, o1, 0, 0, 0);
  }
#pragma unroll
  for (int r = 0; r < 4; ++r) {
    int q = q0 + lhi * 4 + r;
    if (q < Se) {
      float inv = 1.0f / lrow[r];
      size_t base = (size_t)(off + q) * 256 + hh * 32;
      ao[base + l16] = f2b(o0[r] * inv);
      ao[base + 16 + l16] = f2b(o1[r] * inv);
    }
  }
}

// ---------------- masked mean pooling ----------------------------------------
__global__ void k_pool(const float* __restrict__ x, const int* __restrict__ offs,
                       float* __restrict__ emb) {
  int e = blockIdx.x, t = threadIdx.x;
  int off = offs[e], cnt = offs[e + 1] - off;
  float acc = 0.0f;
  for (int r = 0; r < cnt; ++r) acc += x[(size_t)(off + r) * 256 + t];
  emb[e * 256 + t] = acc / (float)max(cnt, 1);
}

// ---------------- prediction head + L2 normalize -----------------------------
__global__ void k_head(const float* __restrict__ emb, const float* __restrict__ w1,
                       const float* __restrict__ b1, const float* __restrict__ w2,
                       const float* __restrict__ b2, float* __restrict__ out) {
  __shared__ float le[256], hb[256], vec[3];
  int e = blockIdx.x, t = threadIdx.x;
  le[t] = emb[e * 256 + t];
  __syncthreads();
  float acc = b1[t];
  const float* wr = w1 + t * 256;
#pragma unroll 8
  for (int k = 0; k < 256; ++k) acc += le[k] * wr[k];
  hb[t] = fmaxf(acc, 0.0f);
  __syncthreads();
  if (t < 3) {
    float a = b2[t];
    const float* w = w2 + t * 256;
    for (int k = 0; k < 256; ++k) a += hb[k] * w[k];
    vec[t] = a;
  }
  __syncthreads();
  if (t < 3) {
    float n = sqrtf(vec[0] * vec[0] + vec[1] * vec[1] + vec[2] * vec[2]);
    out[e * 3 + t] = vec[t] / (n + 1e-8f);
  }
}

// ---------------- launch ------------------------------------------------------
extern "C" void kernel_launch(void* const* d_in, const int* in_sizes, int n_in,
                              void* d_out, int out_size, void* d_ws, size_t ws_size,
                              hipStream_t stream) {
  const float* dom_emb = (const float*)d_in[0];
  const float* geometry = (const float*)d_in[1];
  const float* geo_w1 = (const float*)d_in[2];
  const float* geo_b1 = (const float*)d_in[3];
  const float* geo_w2 = (const float*)d_in[4];
  const float* geo_b2 = (const float*)d_in[5];
  const float* qkv_w = (const float*)d_in[6];
  const float* qkv_b = (const float*)d_in[7];
  const float* out_w = (const float*)d_in[8];
  const float* out_b = (const float*)d_in[9];
  const float* ln1_w = (const float*)d_in[10];
  const float* ln1_b = (const float*)d_in[11];
  const float* ln2_w = (const float*)d_in[12];
  const float* ln2_b = (const float*)d_in[13];
  const float* ffn_w1 = (const float*)d_in[14];
  const float* ffn_b1 = (const float*)d_in[15];
  const float* ffn_w2 = (const float*)d_in[16];
  const float* ffn_b2 = (const float*)d_in[17];
  const float* head_w1 = (const float*)d_in[18];
  const float* head_b1 = (const float*)d_in[19];
  const float* head_w2 = (const float*)d_in[20];
  const float* head_b2 = (const float*)d_in[21];
  const int* dom_ids = (const int*)d_in[22];
  const int* d2e = (const int*)d_in[23];

  char* ws = (char*)d_ws;
  constexpr size_t OFF_OFFS = 0;                              // 65*4 -> 512
  constexpr size_t OFF_WBF = 512;                             // 3145728 elems bf16
  constexpr size_t OFF_GE = OFF_WBF + 3145728ull * 2;         // 5160*256*4
  constexpr size_t OFF_X = (OFF_GE + 5283840ull + 255) & ~255ull;
  constexpr size_t OFF_H = OFF_X + (size_t)T_ * 256 * 4;      // bf16 T x 256
  constexpr size_t OFF_BIG = OFF_H + (size_t)T_ * 256 * 2;    // bf16 T x 1024
  constexpr size_t OFF_EMB = OFF_BIG + (size_t)T_ * 1024 * 2; // f32 64 x 256

  int* offs = (int*)(ws + OFF_OFFS);
  u16* wbf = (u16*)(ws + OFF_WBF);
  u16* wbf_qkv = wbf;                  // L*768*256
  u16* wbf_out = wbf + 786432;         // L*256*256
  u16* wbf_f1 = wbf + 1048576;         // L*1024*256
  u16* wbf_f2 = wbf + 2097152;         // L*256*1024
  float* ge = (float*)(ws + OFF_GE);
  float* x = (float*)(ws + OFF_X);
  u16* h = (u16*)(ws + OFF_H);
  u16* big = (u16*)(ws + OFF_BIG);
  float* emb = (float*)(ws + OFF_EMB);

  k_offsets<<<1, 128, 0, stream>>>(d2e, offs);
  k_f2b<<<256, 256, 0, stream>>>(qkv_w, wbf_qkv, L_ * 768 * 256);
  k_f2b<<<128, 256, 0, stream>>>(out_w, wbf_out, L_ * 256 * 256);
  k_f2b<<<256, 256, 0, stream>>>(ffn_w1, wbf_f1, L_ * 1024 * 256);
  k_f2b<<<256, 256, 0, stream>>>(ffn_w2, wbf_f2, L_ * 256 * 1024);
  k_geo<<<NSENS_, 128, 0, stream>>>(geometry, geo_w1, geo_b1, geo_w2, geo_b2, ge);
  k_feat<<<(T_ * 64) / 256, 256, 0, stream>>>((const float4*)dom_emb, (const float4*)ge,
                                              dom_ids, (float4*)x);
  for (int l = 0; l < L_; ++l) {
    k_ln<<<T_ / 4, 256, 0, stream>>>(x, ln1_w + l * 256, ln1_b + l * 256, h);
    k_gemm<0><<<dim3(6, T_ / 128), 256, 0, stream>>>(h, wbf_qkv + l * 196608, qkv_b + l * 768,
                                                     big, T_, 768, 256);
    k_attn<<<dim3(12, H_, B_), 256, 0, stream>>>(big, offs, h);
    k_gemm<2><<<dim3(2, T_ / 128), 256, 0, stream>>>(h, wbf_out + l * 65536, out_b + l * 256,
                                                     x, T_, 256, 256);
    k_ln<<<T_ / 4, 256, 0, stream>>>(x, ln2_w + l * 256, ln2_b + l * 256, h);
    k_gemm<1><<<dim3(8, T_ / 128), 256, 0, stream>>>(h, wbf_f1 + l * 262144, ffn_b1 + l * 1024,
                                                     big, T_, 1024, 256);
    k_gemm<2><<<dim3(2, T_ / 128), 256, 0, stream>>>(big, wbf_f2 + l * 262144, ffn_b2 + l * 256,
                                                     x, T_, 256, 1024);
  }
  k_pool<<<B_, 256, 0, stream>>>(x, offs, emb);
  k_head<<<B_, 256, 0, stream>>>(emb, head_w1, head_b1, head_w2, head_b2, (float*)d_out);
}

// Round 2
// 1378.862 us; speedup vs baseline: 1.1863x; 1.1863x over previous
//
#include <hip/hip_runtime.h>
#include <stdint.h>

typedef unsigned short u16;
typedef uint32_t u32;
typedef __bf16 bf16x8 __attribute__((ext_vector_type(8)));
typedef float f32x4 __attribute__((ext_vector_type(4)));

constexpr int T_ = 32768, D_ = 256, H_ = 8, L_ = 4, B_ = 64, NSENS_ = 5160;

__device__ __forceinline__ u16 f2b(float f) {
  uint32_t u = __builtin_bit_cast(uint32_t, f);
  u += 0x7fffu + ((u >> 16) & 1u);
  return (u16)(u >> 16);
}
__device__ __forceinline__ float b2f(u16 h) {
  uint32_t u = ((uint32_t)h) << 16;
  return __builtin_bit_cast(float, u);
}

__device__ __forceinline__ void gload16(const void* g, void* l) {
  __builtin_amdgcn_global_load_lds(
      (const __attribute__((address_space(1))) void*)g,
      (__attribute__((address_space(3))) void*)l, 16, 0, 0);
}

// ---------------- offsets via binary search (sorted dom_to_event_idx) --------
__global__ void k_offsets(const int* __restrict__ d2e, int* __restrict__ offs) {
  int t = threadIdx.x;
  if (t > B_) return;
  int lo = 0, hi = T_;
  while (lo < hi) { int mid = (lo + hi) >> 1; if (d2e[mid] < t) lo = mid + 1; else hi = mid; }
  offs[t] = lo;
}

// ---------------- f32 -> bf16 weight conversion ------------------------------
__global__ void k_f2b(const float* __restrict__ s, u16* __restrict__ d, int n) {
  int i = blockIdx.x * blockDim.x + threadIdx.x;
  int str = gridDim.x * blockDim.x;
  for (; i < n; i += str) d[i] = f2b(s[i]);
}

// ---------------- geo MLP per sensor -----------------------------------------
__global__ void k_geo(const float* __restrict__ geom, const float* __restrict__ w1,
                      const float* __restrict__ b1, const float* __restrict__ w2,
                      const float* __restrict__ b2, float* __restrict__ ge) {
  __shared__ float h1[128];
  int s = blockIdx.x, t = threadIdx.x;
  float g0 = geom[s * 3 + 0] * (1.0f / 500.0f);
  float g1 = geom[s * 3 + 1] * (1.0f / 500.0f);
  float g2 = geom[s * 3 + 2] * (1.0f / 500.0f);
  float a = g0 * w1[t * 3 + 0] + g1 * w1[t * 3 + 1] + g2 * w1[t * 3 + 2] + b1[t];
  h1[t] = 0.5f * a * (1.0f + erff(a * 0.70710678118654752f));
  __syncthreads();
  for (int c = t; c < 256; c += 128) {
    float acc = b2[c];
    const float* wr = w2 + c * 128;
#pragma unroll 8
    for (int k = 0; k < 128; ++k) acc += h1[k] * wr[k];
    ge[s * 256 + c] = acc;
  }
}

// ---------------- feat = dom_embeddings + ge[dom_ids] ------------------------
__global__ void k_feat(const float4* __restrict__ de, const float4* __restrict__ ge,
                       const int* __restrict__ dom_ids, float4* __restrict__ x) {
  int i = blockIdx.x * blockDim.x + threadIdx.x;
  if (i >= T_ * 64) return;
  int row = i >> 6, c = i & 63;
  int sid = dom_ids[row];
  float4 a = de[i];
  float4 b = ge[sid * 64 + c];
  float4 o;
  o.x = a.x + b.x; o.y = a.y + b.y; o.z = a.z + b.z; o.w = a.w + b.w;
  x[i] = o;
}

// ---------------- LayerNorm: f32 in -> bf16 out ------------------------------
__global__ void k_ln(const float* __restrict__ x, const float* __restrict__ w,
                     const float* __restrict__ b, u16* __restrict__ h) {
  int row = blockIdx.x * 4 + (threadIdx.x >> 6);
  int lane = threadIdx.x & 63;
  const float4 v = *(const float4*)(x + (size_t)row * 256 + lane * 4);
  float s = v.x + v.y + v.z + v.w;
  float q = v.x * v.x + v.y * v.y + v.z * v.z + v.w * v.w;
#pragma unroll
  for (int m = 1; m < 64; m <<= 1) { s += __shfl_xor(s, m); q += __shfl_xor(q, m); }
  float mean = s * (1.0f / 256.0f);
  float var = fmaxf(q * (1.0f / 256.0f) - mean * mean, 0.0f);
  float rs = 1.0f / sqrtf(var + 1e-5f);
  float4 wv = *(const float4*)(w + lane * 4);
  float4 bv = *(const float4*)(b + lane * 4);
  ushort4 o;
  o.x = f2b((v.x - mean) * rs * wv.x + bv.x);
  o.y = f2b((v.y - mean) * rs * wv.y + bv.y);
  o.z = f2b((v.z - mean) * rs * wv.z + bv.z);
  o.w = f2b((v.w - mean) * rs * wv.w + bv.w);
  *(ushort4*)(h + (size_t)row * 256 + lane * 4) = o;
}

// ---------------- bf16 MFMA GEMM: C = A(MxK) * W(NxK)^T + bias ---------------
// EPI: 0 = bf16 out, 1 = relu -> bf16 out, 2 = f32 residual accumulate (x += C)
template <int EPI>
__global__ __launch_bounds__(256) void k_gemm(const u16* __restrict__ A, const u16* __restrict__ W,
                                              const float* __restrict__ bias, void* __restrict__ out,
                                              int M, int N, int K) {
  __shared__ __align__(16) u16 As[128 * 32];
  __shared__ __align__(16) u16 Ws[128 * 32];
  const int tid = threadIdx.x, lane = tid & 63, wv = tid >> 6;
  const int wr = wv >> 1, wc = wv & 1;
  const int m0 = blockIdx.y * 128, n0 = blockIdx.x * 128;
  const int l16 = lane & 15, lhi = lane >> 4;
  f32x4 acc[4][4] = {};
  for (int kt = 0; kt < K; kt += 32) {
    __syncthreads();
#pragma unroll
    for (int c = 0; c < 2; ++c) {
      int bix = wv * 2048 + c * 1024 + lane * 16;
      int rowA = bix >> 6, off = bix & 63;
      const char* ga = (const char*)A + ((size_t)(m0 + rowA) * K + kt) * 2 + off;
      gload16(ga, (char*)As + wv * 2048 + c * 1024);
      const char* gw = (const char*)W + ((size_t)(n0 + rowA) * K + kt) * 2 + off;
      gload16(gw, (char*)Ws + wv * 2048 + c * 1024);
    }
    __syncthreads();
    bf16x8 af[4], bfr[4];
#pragma unroll
    for (int i = 0; i < 4; ++i) {
      af[i] = *(const bf16x8*)((const char*)As + (wr * 64 + i * 16 + l16) * 64 + lhi * 16);
      bfr[i] = *(const bf16x8*)((const char*)Ws + (wc * 64 + i * 16 + l16) * 64 + lhi * 16);
    }
#pragma unroll
    for (int i = 0; i < 4; ++i)
#pragma unroll
      for (int j = 0; j < 4; ++j)
        acc[i][j] = __builtin_amdgcn_mfma_f32_16x16x32_bf16(af[i], bfr[j], acc[i][j], 0, 0, 0);
  }
  float bv[4];
#pragma unroll
  for (int j = 0; j < 4; ++j) bv[j] = bias[n0 + wc * 64 + j * 16 + l16];
#pragma unroll
  for (int i = 0; i < 4; ++i)
#pragma unroll
    for (int j = 0; j < 4; ++j)
#pragma unroll
      for (int r = 0; r < 4; ++r) {
        int m = m0 + wr * 64 + i * 16 + lhi * 4 + r;
        int n = n0 + wc * 64 + j * 16 + l16;
        float val = acc[i][j][r] + bv[j];
        if (EPI == 0) {
          ((u16*)out)[(size_t)m * N + n] = f2b(val);
        } else if (EPI == 1) {
          ((u16*)out)[(size_t)m * N + n] = f2b(fmaxf(val, 0.0f));
        } else {
          ((float*)out)[(size_t)m * N + n] += val;
        }
      }
}

// ---------------- flash attention v2 ------------------------------------------
// Block = (event, 64-q-chunk); 8 waves = 8 heads. K/V staged for ALL heads with
// rotation-swizzled LDS rows; swapped QK^T so softmax stats are lane-local.
__global__ __launch_bounds__(512) void k_attn(const u16* __restrict__ qkv,
                                              const int* __restrict__ offs,
                                              u16* __restrict__ ao) {
  const int e = blockIdx.x, qc = blockIdx.y;
  const int off = offs[e], Se = offs[e + 1] - off;
  if (qc * 64 >= Se) return;
  const int tid = threadIdx.x, lane = tid & 63, h = tid >> 6;
  const int l16 = lane & 15, lhi = lane >> 4;

  // smem: Ks [64][512B], Vs [64][512B], Ps 8 x [16][144B]
  __shared__ __align__(16) u16 smem[16384 + 16384 + 8 * 1152];
  u16* Ks = smem;
  u16* Vs = smem + 16384;
  char* PsW = (char*)(smem + 32768) + h * 2304;

  // Q fragments (hoisted): B-frag Q[q=l16][dim=lhi*8..+7]
  bf16x8 qf[4];
#pragma unroll
  for (int qt = 0; qt < 4; ++qt) {
    int qrow = qc * 64 + qt * 16 + l16;
    int g = off + min(qrow, Se - 1);
    qf[qt] = *(const bf16x8*)(qkv + (size_t)g * 768 + h * 32 + lhi * 8);
  }

  f32x4 ob[4][2] = {};  // O^T frags [qt][dt]: d=lhi*4+r, q=l16
  float m_[4], l_[4];
#pragma unroll
  for (int qt = 0; qt < 4; ++qt) { m_[qt] = -1e30f; l_[qt] = 0.0f; }
  const float scale = 0.17677669529663687f;

  for (int kb = 0; kb < Se; kb += 64) {
    __syncthreads();
    // ---- stage K,V (all heads, full 512B rows, swizzled) ----
#pragma unroll
    for (int i = 0; i < 4; ++i) {
      int idx = i * 512 + tid;
      int row = idx >> 5, c = idx & 31;
      int g = off + min(kb + row, Se - 1);
      const char* gr = (const char*)qkv + (size_t)g * 1536;
      uint4 kvk = *(const uint4*)(gr + 512 + c * 16);
      uint4 kvv = *(const uint4*)(gr + 1024 + c * 16);
      int kc = (c + (row & 15)) & 31;
      int vc = (c + 2 * (row >> 3)) & 31;
      *(uint4*)((char*)Ks + row * 512 + kc * 16) = kvk;
      *(uint4*)((char*)Vs + row * 512 + vc * 16) = kvv;
    }
    __syncthreads();

    // ---- K frags: A[key=l16][dim=lhi*8..+7] ----
    bf16x8 kf[4];
#pragma unroll
    for (int kt = 0; kt < 4; ++kt) {
      int key = kt * 16 + l16;
      int bir = (h * 64 + lhi * 16 + (l16 << 4)) & 511;
      kf[kt] = *(const bf16x8*)((const char*)Ks + key * 512 + bir);
    }
    // ---- V frags: A[d=l16][key=lhi*8+j] via 8 scalar reads ----
    bf16x8 vf[2][2];
#pragma unroll
    for (int dt = 0; dt < 2; ++dt)
#pragma unroll
      for (int k2 = 0; k2 < 2; ++k2) {
        int roff = ((h * 32 + dt * 16 + l16) * 2 + ((k2 * 4 + lhi) << 5)) & 511;
        union { u16 a[8]; bf16x8 v; } u;
#pragma unroll
        for (int j = 0; j < 8; ++j)
          u.a[j] = *(const u16*)((const char*)Vs + (k2 * 32 + lhi * 8 + j) * 512 + roff);
        vf[dt][k2] = u.v;
      }

#pragma unroll
    for (int qt = 0; qt < 4; ++qt) {
      // scores: D[key=lhi*4+r (+16kt)][q=l16]
      f32x4 sc[4];
#pragma unroll
      for (int kt = 0; kt < 4; ++kt) {
        f32x4 z = {};
        sc[kt] = __builtin_amdgcn_mfma_f32_16x16x32_bf16(kf[kt], qf[qt], z, 0, 0, 0);
      }
      float pv[16];
      float pm = -1e30f;
#pragma unroll
      for (int kt = 0; kt < 4; ++kt)
#pragma unroll
        for (int r = 0; r < 4; ++r) {
          int kidx = kb + kt * 16 + lhi * 4 + r;
          float s = (kidx < Se) ? sc[kt][r] * scale : -1e30f;
          pv[kt * 4 + r] = s;
          pm = fmaxf(pm, s);
        }
      pm = fmaxf(pm, __shfl_xor(pm, 16));
      pm = fmaxf(pm, __shfl_xor(pm, 32));
      float mn = fmaxf(m_[qt], pm);
      float csc = __expf(m_[qt] - mn);
      m_[qt] = mn;
      float rs = 0.0f;
#pragma unroll
      for (int i = 0; i < 16; ++i) {
        float ev = __expf(pv[i] - mn);
        pv[i] = ev;
        rs += ev;
      }
      rs += __shfl_xor(rs, 16);
      rs += __shfl_xor(rs, 32);
      l_[qt] = l_[qt] * csc + rs;
#pragma unroll
      for (int dt = 0; dt < 2; ++dt)
#pragma unroll
        for (int r = 0; r < 4; ++r) ob[qt][dt][r] *= csc;
      // P -> LDS: [q=l16][key], packed u32 writes
#pragma unroll
      for (int kt = 0; kt < 4; ++kt)
#pragma unroll
        for (int c = 0; c < 2; ++c) {
          u32 pk = (u32)f2b(pv[kt * 4 + 2 * c]) | ((u32)f2b(pv[kt * 4 + 2 * c + 1]) << 16);
          *(u32*)(PsW + l16 * 144 + (kt * 16 + lhi * 4 + 2 * c) * 2) = pk;
        }
      // PV: O^T[d][q] += V^T-frag x P-frag
#pragma unroll
      for (int k2 = 0; k2 < 2; ++k2) {
        bf16x8 pf = *(const bf16x8*)(PsW + l16 * 144 + k2 * 64 + lhi * 16);
#pragma unroll
        for (int dt = 0; dt < 2; ++dt)
          ob[qt][dt] = __builtin_amdgcn_mfma_f32_16x16x32_bf16(vf[dt][k2], pf, ob[qt][dt], 0, 0, 0);
      }
    }
  }

  // ---- epilogue: O^T -> LDS bounce -> coalesced global stores ----
  __syncthreads();
  char* Oe = (char*)smem + h * 7168;  // [64 q][112B] per wave
#pragma unroll
  for (int qt = 0; qt < 4; ++qt) {
    float inv = 1.0f / l_[qt];
#pragma unroll
    for (int dt = 0; dt < 2; ++dt)
#pragma unroll
      for (int c = 0; c < 2; ++c) {
        u32 pk = (u32)f2b(ob[qt][dt][2 * c] * inv) |
                 ((u32)f2b(ob[qt][dt][2 * c + 1] * inv) << 16);
        *(u32*)(Oe + (qt * 16 + l16) * 112 + (dt * 16 + lhi * 4 + 2 * c) * 2) = pk;
      }
  }
  __builtin_amdgcn_s_waitcnt(0);  // lgkmcnt(0) conservative; wave-internal
  int qrow = qc * 64 + lane;
  if (qrow < Se) {
#pragma unroll
    for (int c = 0; c < 4; ++c) {
      uint4 t = *(const uint4*)(Oe + lane * 112 + c * 16);
      *(uint4*)((char*)ao + (size_t)(off + qrow) * 512 + h * 64 + c * 16) = t;
    }
  }
}

// ---------------- masked mean pooling ----------------------------------------
__global__ void k_pool(const float* __restrict__ x, const int* __restrict__ offs,
                       float* __restrict__ emb) {
  int e = blockIdx.x, t = threadIdx.x;
  int off = offs[e], cnt = offs[e + 1] - off;
  float acc = 0.0f;
  for (int r = 0; r < cnt; ++r) acc += x[(size_t)(off + r) * 256 + t];
  emb[e * 256 + t] = acc / (float)max(cnt, 1);
}

// ---------------- prediction head + L2 normalize -----------------------------
__global__ void k_head(const float* __restrict__ emb, const float* __restrict__ w1,
                       const float* __restrict__ b1, const float* __restrict__ w2,
                       const float* __restrict__ b2, float* __restrict__ out) {
  __shared__ float le[256], hb[256], vec[3];
  int e = blockIdx.x, t = threadIdx.x;
  le[t] = emb[e * 256 + t];
  __syncthreads();
  float acc = b1[t];
  const float* wr = w1 + t * 256;
#pragma unroll 8
  for (int k = 0; k < 256; ++k) acc += le[k] * wr[k];
  hb[t] = fmaxf(acc, 0.0f);
  __syncthreads();
  if (t < 3) {
    float a = b2[t];
    const float* w = w2 + t * 256;
    for (int k = 0; k < 256; ++k) a += hb[k] * w[k];
    vec[t] = a;
  }
  __syncthreads();
  if (t < 3) {
    float n = sqrtf(vec[0] * vec[0] + vec[1] * vec[1] + vec[2] * vec[2]);
    out[e * 3 + t] = vec[t] / (n + 1e-8f);
  }
}

// ---------------- launch ------------------------------------------------------
extern "C" void kernel_launch(void* const* d_in, const int* in_sizes, int n_in,
                              void* d_out, int out_size, void* d_ws, size_t ws_size,
                              hipStream_t stream) {
  const float* dom_emb = (const float*)d_in[0];
  const float* geometry = (const float*)d_in[1];
  const float* geo_w1 = (const float*)d_in[2];
  const float* geo_b1 = (const float*)d_in[3];
  const float* geo_w2 = (const float*)d_in[4];
  const float* geo_b2 = (const float*)d_in[5];
  const float* qkv_w = (const float*)d_in[6];
  const float* qkv_b = (const float*)d_in[7];
  const float* out_w = (const float*)d_in[8];
  const float* out_b = (const float*)d_in[9];
  const float* ln1_w = (const float*)d_in[10];
  const float* ln1_b = (const float*)d_in[11];
  const float* ln2_w = (const float*)d_in[12];
  const float* ln2_b = (const float*)d_in[13];
  const float* ffn_w1 = (const float*)d_in[14];
  const float* ffn_b1 = (const float*)d_in[15];
  const float* ffn_w2 = (const float*)d_in[16];
  const float* ffn_b2 = (const float*)d_in[17];
  const float* head_w1 = (const float*)d_in[18];
  const float* head_b1 = (const float*)d_in[19];
  const float* head_w2 = (const float*)d_in[20];
  const float* head_b2 = (const float*)d_in[21];
  const int* dom_ids = (const int*)d_in[22];
  const int* d2e = (const int*)d_in[23];

  char* ws = (char*)d_ws;
  constexpr size_t OFF_OFFS = 0;                              // 65*4 -> 512
  constexpr size_t OFF_WBF = 512;                             // 3145728 elems bf16
  constexpr size_t OFF_GE = OFF_WBF + 3145728ull * 2;         // 5160*256*4
  constexpr size_t OFF_X = (OFF_GE + 5283840ull + 255) & ~255ull;
  constexpr size_t OFF_H = OFF_X + (size_t)T_ * 256 * 4;      // bf16 T x 256
  constexpr size_t OFF_BIG = OFF_H + (size_t)T_ * 256 * 2;    // bf16 T x 1024
  constexpr size_t OFF_EMB = OFF_BIG + (size_t)T_ * 1024 * 2; // f32 64 x 256

  int* offs = (int*)(ws + OFF_OFFS);
  u16* wbf = (u16*)(ws + OFF_WBF);
  u16* wbf_qkv = wbf;                  // L*768*256
  u16* wbf_out = wbf + 786432;         // L*256*256
  u16* wbf_f1 = wbf + 1048576;         // L*1024*256
  u16* wbf_f2 = wbf + 2097152;         // L*256*1024
  float* ge = (float*)(ws + OFF_GE);
  float* x = (float*)(ws + OFF_X);
  u16* h = (u16*)(ws + OFF_H);
  u16* big = (u16*)(ws + OFF_BIG);
  float* emb = (float*)(ws + OFF_EMB);

  k_offsets<<<1, 128, 0, stream>>>(d2e, offs);
  k_f2b<<<256, 256, 0, stream>>>(qkv_w, wbf_qkv, L_ * 768 * 256);
  k_f2b<<<128, 256, 0, stream>>>(out_w, wbf_out, L_ * 256 * 256);
  k_f2b<<<256, 256, 0, stream>>>(ffn_w1, wbf_f1, L_ * 1024 * 256);
  k_f2b<<<256, 256, 0, stream>>>(ffn_w2, wbf_f2, L_ * 256 * 1024);
  k_geo<<<NSENS_, 128, 0, stream>>>(geometry, geo_w1, geo_b1, geo_w2, geo_b2, ge);
  k_feat<<<(T_ * 64) / 256, 256, 0, stream>>>((const float4*)dom_emb, (const float4*)ge,
                                              dom_ids, (float4*)x);
  for (int l = 0; l < L_; ++l) {
    k_ln<<<T_ / 4, 256, 0, stream>>>(x, ln1_w + l * 256, ln1_b + l * 256, h);
    k_gemm<0><<<dim3(6, T_ / 128), 256, 0, stream>>>(h, wbf_qkv + l * 196608, qkv_b + l * 768,
                                                     big, T_, 768, 256);
    k_attn<<<dim3(B_, 12), 512, 0, stream>>>(big, offs, h);
    k_gemm<2><<<dim3(2, T_ / 128), 256, 0, stream>>>(h, wbf_out + l * 65536, out_b + l * 256,
                                                     x, T_, 256, 256);
    k_ln<<<T_ / 4, 256, 0, stream>>>(x, ln2_w + l * 256, ln2_b + l * 256, h);
    k_gemm<1><<<dim3(8, T_ / 128), 256, 0, stream>>>(h, wbf_f1 + l * 262144, ffn_b1 + l * 1024,
                                                     big, T_, 1024, 256);
    k_gemm<2><<<dim3(2, T_ / 128), 256, 0, stream>>>(big, wbf_f2 + l * 262144, ffn_b2 + l * 256,
                                                     x, T_, 256, 1024);
  }
  k_pool<<<B_, 256, 0, stream>>>(x, offs, emb);
  k_head<<<B_, 256, 0, stream>>>(emb, head_w1, head_b1, head_w2, head_b2, (float*)d_out);
}

// Round 3
// 1228.296 us; speedup vs baseline: 1.3317x; 1.1226x over previous
//
#include <hip/hip_runtime.h>
#include <stdint.h>

typedef unsigned short u16;
typedef uint32_t u32;
typedef __bf16 bf16x8 __attribute__((ext_vector_type(8)));
typedef float f32x4 __attribute__((ext_vector_type(4)));

constexpr int T_ = 32768, D_ = 256, H_ = 8, L_ = 4, B_ = 64, NSENS_ = 5160;

__device__ __forceinline__ u16 f2b(float f) {
  uint32_t u = __builtin_bit_cast(uint32_t, f);
  u += 0x7fffu + ((u >> 16) & 1u);
  return (u16)(u >> 16);
}
__device__ __forceinline__ float b2f(u16 h) {
  uint32_t u = ((uint32_t)h) << 16;
  return __builtin_bit_cast(float, u);
}

__device__ __forceinline__ void gload16(const void* g, void* l) {
  __builtin_amdgcn_global_load_lds(
      (const __attribute__((address_space(1))) void*)g,
      (__attribute__((address_space(3))) void*)l, 16, 0, 0);
}

// ---------------- offsets via binary search (sorted dom_to_event_idx) --------
__global__ void k_offsets(const int* __restrict__ d2e, int* __restrict__ offs) {
  int t = threadIdx.x;
  if (t > B_) return;
  int lo = 0, hi = T_;
  while (lo < hi) { int mid = (lo + hi) >> 1; if (d2e[mid] < t) lo = mid + 1; else hi = mid; }
  offs[t] = lo;
}

// ---------------- f32 -> bf16 weight conversion ------------------------------
__global__ void k_f2b(const float* __restrict__ s, u16* __restrict__ d, int n) {
  int i = blockIdx.x * blockDim.x + threadIdx.x;
  int str = gridDim.x * blockDim.x;
  for (; i < n; i += str) d[i] = f2b(s[i]);
}

// ---------------- geo MLP per sensor -----------------------------------------
__global__ void k_geo(const float* __restrict__ geom, const float* __restrict__ w1,
                      const float* __restrict__ b1, const float* __restrict__ w2,
                      const float* __restrict__ b2, float* __restrict__ ge) {
  __shared__ float h1[128];
  int s = blockIdx.x, t = threadIdx.x;
  float g0 = geom[s * 3 + 0] * (1.0f / 500.0f);
  float g1 = geom[s * 3 + 1] * (1.0f / 500.0f);
  float g2 = geom[s * 3 + 2] * (1.0f / 500.0f);
  float a = g0 * w1[t * 3 + 0] + g1 * w1[t * 3 + 1] + g2 * w1[t * 3 + 2] + b1[t];
  h1[t] = 0.5f * a * (1.0f + erff(a * 0.70710678118654752f));
  __syncthreads();
  for (int c = t; c < 256; c += 128) {
    float acc = b2[c];
    const float* wr = w2 + c * 128;
#pragma unroll 8
    for (int k = 0; k < 128; ++k) acc += h1[k] * wr[k];
    ge[s * 256 + c] = acc;
  }
}

// ---------------- feat = dom_embeddings + ge[dom_ids] ------------------------
__global__ void k_feat(const float4* __restrict__ de, const float4* __restrict__ ge,
                       const int* __restrict__ dom_ids, float4* __restrict__ x) {
  int i = blockIdx.x * blockDim.x + threadIdx.x;
  if (i >= T_ * 64) return;
  int row = i >> 6, c = i & 63;
  int sid = dom_ids[row];
  float4 a = de[i];
  float4 b = ge[sid * 64 + c];
  float4 o;
  o.x = a.x + b.x; o.y = a.y + b.y; o.z = a.z + b.z; o.w = a.w + b.w;
  x[i] = o;
}

// ---------------- LayerNorm: f32 in -> bf16 out ------------------------------
__global__ void k_ln(const float* __restrict__ x, const float* __restrict__ w,
                     const float* __restrict__ b, u16* __restrict__ h) {
  int row = blockIdx.x * 4 + (threadIdx.x >> 6);
  int lane = threadIdx.x & 63;
  const float4 v = *(const float4*)(x + (size_t)row * 256 + lane * 4);
  float s = v.x + v.y + v.z + v.w;
  float q = v.x * v.x + v.y * v.y + v.z * v.z + v.w * v.w;
#pragma unroll
  for (int m = 1; m < 64; m <<= 1) { s += __shfl_xor(s, m); q += __shfl_xor(q, m); }
  float mean = s * (1.0f / 256.0f);
  float var = fmaxf(q * (1.0f / 256.0f) - mean * mean, 0.0f);
  float rs = 1.0f / sqrtf(var + 1e-5f);
  float4 wv = *(const float4*)(w + lane * 4);
  float4 bv = *(const float4*)(b + lane * 4);
  ushort4 o;
  o.x = f2b((v.x - mean) * rs * wv.x + bv.x);
  o.y = f2b((v.y - mean) * rs * wv.y + bv.y);
  o.z = f2b((v.z - mean) * rs * wv.z + bv.z);
  o.w = f2b((v.w - mean) * rs * wv.w + bv.w);
  *(ushort4*)(h + (size_t)row * 256 + lane * 4) = o;
}

// ---------------- bf16 MFMA GEMM v2 ------------------------------------------
// C = A(MxK) * W(NxK)^T + bias. BK=64, st_16x32 swizzled LDS via pre-swizzled
// global_load_lds source, 2-phase double buffer with counted vmcnt, raw
// s_barrier (no vmcnt drain in loop), XCD-bijective block remap.
// EPI: 0 = bf16 out, 1 = relu -> bf16 out, 2 = f32 residual accumulate
template <int EPI>
__global__ __launch_bounds__(256) void k_gemm(const u16* __restrict__ A, const u16* __restrict__ W,
                                              const float* __restrict__ bias, void* __restrict__ out,
                                              int M, int N, int K, int NXB) {
  __shared__ __align__(16) u16 lds[4 * 8192];  // A0,B0 | A1,B1  (16KB tiles)
  const int nb = gridDim.x;
  const int id = blockIdx.x;
  const int gid = (id & 7) * (nb >> 3) + (id >> 3);
  const int by = gid / NXB, bx = gid % NXB;
  const int m0 = by * 128, n0 = bx * 128;
  const int tid = threadIdx.x, lane = tid & 63, wv = tid >> 6;
  const int wr = wv >> 1, wc = wv & 1;
  const int l16 = lane & 15, lhi = lane >> 4;
  f32x4 acc[4][4] = {};
  const int NK = K >> 6;

  auto stage = [&](int buf, int kt) {
    char* lbase = (char*)lds + buf * 32768;
#pragma unroll
    for (int c = 0; c < 4; ++c) {
      int pb = c * 4096 + wv * 1024;          // wave-uniform LDS byte base
      int p = pb + lane * 16;                 // this lane's physical byte
      int o = p ^ (((p >> 9) & 1) << 5);      // logical byte (involution)
      int row = o >> 7, colb = o & 127;
      gload16((const char*)A + ((size_t)(m0 + row) * K) * 2 + kt * 128 + colb, lbase + pb);
      gload16((const char*)W + ((size_t)(n0 + row) * K) * 2 + kt * 128 + colb,
              lbase + 16384 + pb);
    }
  };
  auto compute = [&](int buf) {
    const char* la = (const char*)lds + buf * 32768;
    const char* lb = la + 16384;
#pragma unroll
    for (int ks = 0; ks < 2; ++ks) {
      bf16x8 af[4], bfr[4];
#pragma unroll
      for (int i = 0; i < 4; ++i) {
        int ra = wr * 64 + i * 16 + l16;
        int oa = ra * 128 + ks * 64 + lhi * 16;
        af[i] = *(const bf16x8*)(la + (oa ^ (((oa >> 9) & 1) << 5)));
        int rb = wc * 64 + i * 16 + l16;
        int ob2 = rb * 128 + ks * 64 + lhi * 16;
        bfr[i] = *(const bf16x8*)(lb + (ob2 ^ (((ob2 >> 9) & 1) << 5)));
      }
#pragma unroll
      for (int i = 0; i < 4; ++i)
#pragma unroll
        for (int j = 0; j < 4; ++j)
          acc[i][j] = __builtin_amdgcn_mfma_f32_16x16x32_bf16(af[i], bfr[j], acc[i][j], 0, 0, 0);
    }
  };

  stage(0, 0);
  for (int kt = 0; kt < NK; ++kt) {
    int cur = kt & 1;
    if (kt + 1 < NK) {
      stage(cur ^ 1, kt + 1);
      asm volatile("s_waitcnt vmcnt(8)" ::: "memory");
    } else {
      asm volatile("s_waitcnt vmcnt(0)" ::: "memory");
    }
    __builtin_amdgcn_s_barrier();
    __builtin_amdgcn_sched_barrier(0);
    compute(cur);
    __builtin_amdgcn_sched_barrier(0);
    __builtin_amdgcn_s_barrier();
  }

  float bv[4];
#pragma unroll
  for (int j = 0; j < 4; ++j) bv[j] = bias[n0 + wc * 64 + j * 16 + l16];

  if (EPI <= 1) {
    // bounce through LDS (swizzled) for coalesced 16B stores
    char* ob_ = (char*)lds;
#pragma unroll
    for (int i = 0; i < 4; ++i)
#pragma unroll
      for (int j = 0; j < 4; ++j)
#pragma unroll
        for (int r = 0; r < 4; ++r) {
          int row = wr * 64 + i * 16 + lhi * 4 + r;
          int col = wc * 64 + j * 16 + l16;
          float v = acc[i][j][r] + bv[j];
          if (EPI == 1) v = fmaxf(v, 0.0f);
          int byte = row * 256 + col * 2;
          *(u16*)(ob_ + (byte ^ ((row & 3) << 5))) = f2b(v);
        }
    __syncthreads();
    int row2 = tid >> 1, half = tid & 1;
    char* dst = (char*)out + ((size_t)(m0 + row2) * N + n0) * 2 + half * 128;
#pragma unroll
    for (int c2 = 0; c2 < 8; ++c2) {
      int byte = row2 * 256 + half * 128 + c2 * 16;
      uint4 t = *(const uint4*)(ob_ + (byte ^ ((row2 & 3) << 5)));
      *(uint4*)(dst + c2 * 16) = t;
    }
  } else {
#pragma unroll
    for (int i = 0; i < 4; ++i)
#pragma unroll
      for (int j = 0; j < 4; ++j)
#pragma unroll
        for (int r = 0; r < 4; ++r) {
          int m = m0 + wr * 64 + i * 16 + lhi * 4 + r;
          int n = n0 + wc * 64 + j * 16 + l16;
          ((float*)out)[(size_t)m * N + n] += acc[i][j][r] + bv[j];
        }
  }
}

// ---------------- flash attention (r1 structure, unchanged) -------------------
__global__ __launch_bounds__(512) void k_attn(const u16* __restrict__ qkv,
                                              const int* __restrict__ offs,
                                              u16* __restrict__ ao) {
  const int e = blockIdx.x, qc = blockIdx.y;
  const int off = offs[e], Se = offs[e + 1] - off;
  if (qc * 64 >= Se) return;
  const int tid = threadIdx.x, lane = tid & 63, h = tid >> 6;
  const int l16 = lane & 15, lhi = lane >> 4;

  __shared__ __align__(16) u16 smem[16384 + 16384 + 8 * 1152];
  u16* Ks = smem;
  u16* Vs = smem + 16384;
  char* PsW = (char*)(smem + 32768) + h * 2304;

  bf16x8 qf[4];
#pragma unroll
  for (int qt = 0; qt < 4; ++qt) {
    int qrow = qc * 64 + qt * 16 + l16;
    int g = off + min(qrow, Se - 1);
    qf[qt] = *(const bf16x8*)(qkv + (size_t)g * 768 + h * 32 + lhi * 8);
  }

  f32x4 ob[4][2] = {};
  float m_[4], l_[4];
#pragma unroll
  for (int qt = 0; qt < 4; ++qt) { m_[qt] = -1e30f; l_[qt] = 0.0f; }
  const float scale = 0.17677669529663687f;

  for (int kb = 0; kb < Se; kb += 64) {
    __syncthreads();
#pragma unroll
    for (int i = 0; i < 4; ++i) {
      int idx = i * 512 + tid;
      int row = idx >> 5, c = idx & 31;
      int g = off + min(kb + row, Se - 1);
      const char* gr = (const char*)qkv + (size_t)g * 1536;
      uint4 kvk = *(const uint4*)(gr + 512 + c * 16);
      uint4 kvv = *(const uint4*)(gr + 1024 + c * 16);
      int kc = (c + (row & 15)) & 31;
      int vc = (c + 2 * (row >> 3)) & 31;
      *(uint4*)((char*)Ks + row * 512 + kc * 16) = kvk;
      *(uint4*)((char*)Vs + row * 512 + vc * 16) = kvv;
    }
    __syncthreads();

    bf16x8 kf[4];
#pragma unroll
    for (int kt = 0; kt < 4; ++kt) {
      int key = kt * 16 + l16;
      int bir = (h * 64 + lhi * 16 + (l16 << 4)) & 511;
      kf[kt] = *(const bf16x8*)((const char*)Ks + key * 512 + bir);
    }
    bf16x8 vf[2][2];
#pragma unroll
    for (int dt = 0; dt < 2; ++dt)
#pragma unroll
      for (int k2 = 0; k2 < 2; ++k2) {
        int roff = ((h * 32 + dt * 16 + l16) * 2 + ((k2 * 4 + lhi) << 5)) & 511;
        union { u16 a[8]; bf16x8 v; } u;
#pragma unroll
        for (int j = 0; j < 8; ++j)
          u.a[j] = *(const u16*)((const char*)Vs + (k2 * 32 + lhi * 8 + j) * 512 + roff);
        vf[dt][k2] = u.v;
      }

#pragma unroll
    for (int qt = 0; qt < 4; ++qt) {
      f32x4 sc[4];
#pragma unroll
      for (int kt = 0; kt < 4; ++kt) {
        f32x4 z = {};
        sc[kt] = __builtin_amdgcn_mfma_f32_16x16x32_bf16(kf[kt], qf[qt], z, 0, 0, 0);
      }
      float pv[16];
      float pm = -1e30f;
#pragma unroll
      for (int kt = 0; kt < 4; ++kt)
#pragma unroll
        for (int r = 0; r < 4; ++r) {
          int kidx = kb + kt * 16 + lhi * 4 + r;
          float s = (kidx < Se) ? sc[kt][r] * scale : -1e30f;
          pv[kt * 4 + r] = s;
          pm = fmaxf(pm, s);
        }
      pm = fmaxf(pm, __shfl_xor(pm, 16));
      pm = fmaxf(pm, __shfl_xor(pm, 32));
      float mn = fmaxf(m_[qt], pm);
      float csc = __expf(m_[qt] - mn);
      m_[qt] = mn;
      float rs = 0.0f;
#pragma unroll
      for (int i = 0; i < 16; ++i) {
        float ev = __expf(pv[i] - mn);
        pv[i] = ev;
        rs += ev;
      }
      rs += __shfl_xor(rs, 16);
      rs += __shfl_xor(rs, 32);
      l_[qt] = l_[qt] * csc + rs;
#pragma unroll
      for (int dt = 0; dt < 2; ++dt)
#pragma unroll
        for (int r = 0; r < 4; ++r) ob[qt][dt][r] *= csc;
#pragma unroll
      for (int kt = 0; kt < 4; ++kt)
#pragma unroll
        for (int c = 0; c < 2; ++c) {
          u32 pk = (u32)f2b(pv[kt * 4 + 2 * c]) | ((u32)f2b(pv[kt * 4 + 2 * c + 1]) << 16);
          *(u32*)(PsW + l16 * 144 + (kt * 16 + lhi * 4 + 2 * c) * 2) = pk;
        }
#pragma unroll
      for (int k2 = 0; k2 < 2; ++k2) {
        bf16x8 pf = *(const bf16x8*)(PsW + l16 * 144 + k2 * 64 + lhi * 16);
#pragma unroll
        for (int dt = 0; dt < 2; ++dt)
          ob[qt][dt] = __builtin_amdgcn_mfma_f32_16x16x32_bf16(vf[dt][k2], pf, ob[qt][dt], 0, 0, 0);
      }
    }
  }

  __syncthreads();
  char* Oe = (char*)smem + h * 7168;
#pragma unroll
  for (int qt = 0; qt < 4; ++qt) {
    float inv = 1.0f / l_[qt];
#pragma unroll
    for (int dt = 0; dt < 2; ++dt)
#pragma unroll
      for (int c = 0; c < 2; ++c) {
        u32 pk = (u32)f2b(ob[qt][dt][2 * c] * inv) |
                 ((u32)f2b(ob[qt][dt][2 * c + 1] * inv) << 16);
        *(u32*)(Oe + (qt * 16 + l16) * 112 + (dt * 16 + lhi * 4 + 2 * c) * 2) = pk;
      }
  }
  __builtin_amdgcn_s_waitcnt(0);
  int qrow = qc * 64 + lane;
  if (qrow < Se) {
#pragma unroll
    for (int c = 0; c < 4; ++c) {
      uint4 t = *(const uint4*)(Oe + lane * 112 + c * 16);
      *(uint4*)((char*)ao + (size_t)(off + qrow) * 512 + h * 64 + c * 16) = t;
    }
  }
}

// ---------------- masked mean pooling: split-K partials ----------------------
__global__ void k_pool(const float* __restrict__ x, const int* __restrict__ offs,
                       float* __restrict__ pws) {
  int e = blockIdx.x, s = blockIdx.y, t = threadIdx.x;
  int off = offs[e], cnt = offs[e + 1] - off;
  int r0 = (cnt * s) >> 4, r1 = (cnt * (s + 1)) >> 4;
  float acc = 0.0f;
  for (int r = r0; r < r1; ++r) acc += x[(size_t)(off + r) * 256 + t];
  pws[((e << 4) + s) * 256 + t] = acc;
}

// ---------------- prediction head + L2 normalize -----------------------------
__global__ void k_head(const float* __restrict__ pws, const int* __restrict__ offs,
                       const float* __restrict__ w1, const float* __restrict__ b1,
                       const float* __restrict__ w2, const float* __restrict__ b2,
                       float* __restrict__ out) {
  __shared__ float le[256], hb[256], vec[3];
  int e = blockIdx.x, t = threadIdx.x;
  int cnt = offs[e + 1] - offs[e];
  float acc0 = 0.0f;
#pragma unroll
  for (int s = 0; s < 16; ++s) acc0 += pws[((e << 4) + s) * 256 + t];
  le[t] = acc0 / (float)max(cnt, 1);
  __syncthreads();
  float acc = b1[t];
  const float* wr = w1 + t * 256;
#pragma unroll 8
  for (int k = 0; k < 256; ++k) acc += le[k] * wr[k];
  hb[t] = fmaxf(acc, 0.0f);
  __syncthreads();
  if (t < 3) {
    float a = b2[t];
    const float* w = w2 + t * 256;
    for (int k = 0; k < 256; ++k) a += hb[k] * w[k];
    vec[t] = a;
  }
  __syncthreads();
  if (t < 3) {
    float n = sqrtf(vec[0] * vec[0] + vec[1] * vec[1] + vec[2] * vec[2]);
    out[e * 3 + t] = vec[t] / (n + 1e-8f);
  }
}

// ---------------- launch ------------------------------------------------------
extern "C" void kernel_launch(void* const* d_in, const int* in_sizes, int n_in,
                              void* d_out, int out_size, void* d_ws, size_t ws_size,
                              hipStream_t stream) {
  const float* dom_emb = (const float*)d_in[0];
  const float* geometry = (const float*)d_in[1];
  const float* geo_w1 = (const float*)d_in[2];
  const float* geo_b1 = (const float*)d_in[3];
  const float* geo_w2 = (const float*)d_in[4];
  const float* geo_b2 = (const float*)d_in[5];
  const float* qkv_w = (const float*)d_in[6];
  const float* qkv_b = (const float*)d_in[7];
  const float* out_w = (const float*)d_in[8];
  const float* out_b = (const float*)d_in[9];
  const float* ln1_w = (const float*)d_in[10];
  const float* ln1_b = (const float*)d_in[11];
  const float* ln2_w = (const float*)d_in[12];
  const float* ln2_b = (const float*)d_in[13];
  const float* ffn_w1 = (const float*)d_in[14];
  const float* ffn_b1 = (const float*)d_in[15];
  const float* ffn_w2 = (const float*)d_in[16];
  const float* ffn_b2 = (const float*)d_in[17];
  const float* head_w1 = (const float*)d_in[18];
  const float* head_b1 = (const float*)d_in[19];
  const float* head_w2 = (const float*)d_in[20];
  const float* head_b2 = (const float*)d_in[21];
  const int* dom_ids = (const int*)d_in[22];
  const int* d2e = (const int*)d_in[23];

  char* ws = (char*)d_ws;
  constexpr size_t OFF_OFFS = 0;
  constexpr size_t OFF_WBF = 512;
  constexpr size_t OFF_GE = OFF_WBF + 3145728ull * 2;
  constexpr size_t OFF_X = (OFF_GE + 5283840ull + 255) & ~255ull;
  constexpr size_t OFF_H = OFF_X + (size_t)T_ * 256 * 4;
  constexpr size_t OFF_BIG = OFF_H + (size_t)T_ * 256 * 2;
  constexpr size_t OFF_PWS = OFF_BIG + (size_t)T_ * 1024 * 2;  // 64*16*256 f32 = 1MB

  int* offs = (int*)(ws + OFF_OFFS);
  u16* wbf = (u16*)(ws + OFF_WBF);
  u16* wbf_qkv = wbf;
  u16* wbf_out = wbf + 786432;
  u16* wbf_f1 = wbf + 1048576;
  u16* wbf_f2 = wbf + 2097152;
  float* ge = (float*)(ws + OFF_GE);
  float* x = (float*)(ws + OFF_X);
  u16* h = (u16*)(ws + OFF_H);
  u16* big = (u16*)(ws + OFF_BIG);
  float* pws = (float*)(ws + OFF_PWS);

  k_offsets<<<1, 128, 0, stream>>>(d2e, offs);
  k_f2b<<<256, 256, 0, stream>>>(qkv_w, wbf_qkv, L_ * 768 * 256);
  k_f2b<<<128, 256, 0, stream>>>(out_w, wbf_out, L_ * 256 * 256);
  k_f2b<<<256, 256, 0, stream>>>(ffn_w1, wbf_f1, L_ * 1024 * 256);
  k_f2b<<<256, 256, 0, stream>>>(ffn_w2, wbf_f2, L_ * 256 * 1024);
  k_geo<<<NSENS_, 128, 0, stream>>>(geometry, geo_w1, geo_b1, geo_w2, geo_b2, ge);
  k_feat<<<(T_ * 64) / 256, 256, 0, stream>>>((const float4*)dom_emb, (const float4*)ge,
                                              dom_ids, (float4*)x);
  for (int l = 0; l < L_; ++l) {
    k_ln<<<T_ / 4, 256, 0, stream>>>(x, ln1_w + l * 256, ln1_b + l * 256, h);
    k_gemm<0><<<6 * 256, 256, 0, stream>>>(h, wbf_qkv + l * 196608, qkv_b + l * 768,
                                           big, T_, 768, 256, 6);
    k_attn<<<dim3(B_, 12), 512, 0, stream>>>(big, offs, h);
    k_gemm<2><<<2 * 256, 256, 0, stream>>>(h, wbf_out + l * 65536, out_b + l * 256,
                                           x, T_, 256, 256, 2);
    k_ln<<<T_ / 4, 256, 0, stream>>>(x, ln2_w + l * 256, ln2_b + l * 256, h);
    k_gemm<1><<<8 * 256, 256, 0, stream>>>(h, wbf_f1 + l * 262144, ffn_b1 + l * 1024,
                                           big, T_, 1024, 256, 8);
    k_gemm<2><<<2 * 256, 256, 0, stream>>>(big, wbf_f2 + l * 262144, ffn_b2 + l * 256,
                                           x, T_, 256, 1024, 2);
  }
  k_pool<<<dim3(B_, 16), 256, 0, stream>>>(x, offs, pws);
  k_head<<<B_, 256, 0, stream>>>(pws, offs, head_w1, head_b1, head_w2, head_b2, (float*)d_out);
}